// Round 1
// baseline (498.459 us; speedup 1.0000x reference)
//
#include <hip/hip_runtime.h>

#define B_ 2
#define S_ 2048
#define H_ 2048
#define NH_ 32
#define NKV_ 8
#define HD_ 64

typedef short short8 __attribute__((ext_vector_type(8)));
typedef float f32x4 __attribute__((ext_vector_type(4)));

__device__ __forceinline__ float bf2f(unsigned short u) {
  union { unsigned int i; float f; } v; v.i = ((unsigned int)u) << 16; return v.f;
}
__device__ __forceinline__ unsigned short f2bf(float f) {
  union { float f; unsigned int i; } v; v.f = f;
  unsigned int u = v.i;
  u += 0x7fffu + ((u >> 16) & 1u);
  return (unsigned short)(u >> 16);
}

// ---------------- weight transpose + cast: W[K][N] f32 -> Wt[N][K] bf16 ----------------
__global__ __launch_bounds__(256) void transpose_cast(const float* __restrict__ W,
                                                      unsigned short* __restrict__ Wt,
                                                      int N, int K) {
  __shared__ float tile[32][33];
  int n0 = blockIdx.x * 32, k0 = blockIdx.y * 32;
  int tx = threadIdx.x & 31;
  int ty = threadIdx.x >> 5; // 0..7
#pragma unroll
  for (int i = 0; i < 32; i += 8)
    tile[ty + i][tx] = W[(size_t)(k0 + ty + i) * N + n0 + tx];
  __syncthreads();
#pragma unroll
  for (int i = 0; i < 32; i += 8)
    Wt[(size_t)(n0 + ty + i) * K + k0 + tx] = f2bf(tile[tx][ty + i]);
}

// ---------------- V transpose: P1 v-region (b,s | kv,d) -> Vt[b][kv][d][s] ----------------
__global__ __launch_bounds__(256) void vtrans_kernel(const unsigned short* __restrict__ P1,
                                                     unsigned short* __restrict__ Vt) {
  // grid: (S/32, HD/32, B*NKV)
  __shared__ unsigned short tile[32][33];
  int s0 = blockIdx.x * 32, d0 = blockIdx.y * 32, bk = blockIdx.z;
  int b = bk >> 3, kv = bk & 7;
  int tx = threadIdx.x & 31, ty = threadIdx.x >> 5;
#pragma unroll
  for (int i = 0; i < 32; i += 8)
    tile[ty + i][tx] = P1[(size_t)(b * S_ + s0 + ty + i) * 3072 + 2560 + kv * 64 + d0 + tx];
  __syncthreads();
#pragma unroll
  for (int i = 0; i < 32; i += 8)
    Vt[(size_t)(bk * 64 + d0 + ty + i) * S_ + s0 + tx] = tile[tx][ty + i];
}

// ---------------- RoPE combine: Q = rope(P1q+P2q)*SCALE, K = rope(P1k+P2k) ----------------
__global__ __launch_bounds__(256) void combine_rope(const unsigned short* __restrict__ P1,
                                                    const unsigned short* __restrict__ P2,
                                                    const float* __restrict__ cosT,
                                                    const float* __restrict__ sinT,
                                                    unsigned short* __restrict__ Qb,
                                                    unsigned short* __restrict__ Kb) {
  int id = blockIdx.x * 256 + threadIdx.x;   // total B*S*640
  int row = id / 640;                        // b*S + s
  int grp = id - row * 640;
  int b = row >> 11;
  int s = row & 2047;
  bool isQ = grp < 512;
  int n = isQ ? grp * 4 : (grp - 512) * 4;
  int h = n >> 6;
  int d = n & 63;
  int base = isQ ? 0 : 2048;
  const int ld1 = 3072, ld2 = 2560;
  int pd = (d < 32) ? d + 32 : d - 32;
  float sign = (d < 32) ? -1.f : 1.f;
  int pcol = base + h * 64 + pd;

  ushort4 a1 = *(const ushort4*)&P1[(size_t)row * ld1 + base + n];
  ushort4 a2 = *(const ushort4*)&P2[(size_t)row * ld2 + base + n];
  ushort4 b1 = *(const ushort4*)&P1[(size_t)row * ld1 + pcol];
  ushort4 b2 = *(const ushort4*)&P2[(size_t)row * ld2 + pcol];
  float4 cv = *(const float4*)&cosT[(size_t)row * 64 + d];
  float4 sv = *(const float4*)&sinT[(size_t)row * 64 + d];
  float scale = isQ ? 0.125f : 1.0f;

  float xs[4] = { bf2f(a1.x) + bf2f(a2.x), bf2f(a1.y) + bf2f(a2.y),
                  bf2f(a1.z) + bf2f(a2.z), bf2f(a1.w) + bf2f(a2.w) };
  float xp[4] = { bf2f(b1.x) + bf2f(b2.x), bf2f(b1.y) + bf2f(b2.y),
                  bf2f(b1.z) + bf2f(b2.z), bf2f(b1.w) + bf2f(b2.w) };
  float cc[4] = { cv.x, cv.y, cv.z, cv.w };
  float ss[4] = { sv.x, sv.y, sv.z, sv.w };
  ushort4 o;
  unsigned short* op = (unsigned short*)&o;
#pragma unroll
  for (int i = 0; i < 4; ++i)
    op[i] = f2bf((xs[i] * cc[i] + sign * xp[i] * ss[i]) * scale);

  if (isQ)
    *(ushort4*)&Qb[((size_t)(b * NH_ + h) * S_ + s) * HD_ + d] = o;
  else
    *(ushort4*)&Kb[((size_t)(b * NKV_ + h) * S_ + s) * HD_ + d] = o;
}

// ---------------- 128x128 GEMM: C[M][N] = A[M][K] * Bt[N][K]^T ----------------
// A is f32 (AF32=1) or bf16; output f32 (OF32=1) or bf16.
template <int AF32, int OF32>
__global__ __launch_bounds__(256) void gemm128(const void* __restrict__ Av,
                                               const unsigned short* __restrict__ Bt,
                                               void* __restrict__ Cv,
                                               int M, int N, int K) {
  __shared__ unsigned short lA[128 * 40]; // [128][32] padded to 40 (stride 80B)
  __shared__ unsigned short lB[128 * 40];
  int bn = blockIdx.x, bm = blockIdx.y;
  int t = threadIdx.x;
  int w = t >> 6, l = t & 63, g = l >> 4, c = l & 15;
  int wr = w >> 1, wc = w & 1;

  f32x4 acc[4][4];
#pragma unroll
  for (int m = 0; m < 4; ++m)
#pragma unroll
    for (int n = 0; n < 4; ++n) acc[m][n] = 0.f;

  for (int k0 = 0; k0 < K; k0 += 32) {
    __syncthreads();
    if constexpr (AF32) {
      const float* Af = (const float*)Av;
#pragma unroll
      for (int p = 0; p < 4; ++p) {
        int f = p * 256 + t;
        int row = f >> 3, seg = f & 7;
        float4 v = *(const float4*)(Af + (size_t)(bm * 128 + row) * K + k0 + seg * 4);
        ushort4 ov;
        ov.x = f2bf(v.x); ov.y = f2bf(v.y); ov.z = f2bf(v.z); ov.w = f2bf(v.w);
        *(ushort4*)&lA[row * 40 + seg * 4] = ov;
      }
    } else {
      const unsigned short* Ab = (const unsigned short*)Av;
#pragma unroll
      for (int p = 0; p < 2; ++p) {
        int f = p * 256 + t;
        int row = f >> 2, seg = f & 3;
        *(int4*)&lA[row * 40 + seg * 8] =
            *(const int4*)(Ab + (size_t)(bm * 128 + row) * K + k0 + seg * 8);
      }
    }
#pragma unroll
    for (int p = 0; p < 2; ++p) {
      int f = p * 256 + t;
      int row = f >> 2, seg = f & 3;
      *(int4*)&lB[row * 40 + seg * 8] =
          *(const int4*)(Bt + (size_t)(bn * 128 + row) * K + k0 + seg * 8);
    }
    __syncthreads();

    short8 a[4], bfr[4];
#pragma unroll
    for (int m = 0; m < 4; ++m)
      a[m] = *(const short8*)&lA[(wr * 64 + m * 16 + c) * 40 + g * 8];
#pragma unroll
    for (int n = 0; n < 4; ++n)
      bfr[n] = *(const short8*)&lB[(wc * 64 + n * 16 + c) * 40 + g * 8];
#pragma unroll
    for (int m = 0; m < 4; ++m)
#pragma unroll
      for (int n = 0; n < 4; ++n)
        acc[m][n] = __builtin_amdgcn_mfma_f32_16x16x32_bf16(a[m], bfr[n], acc[m][n], 0, 0, 0);
  }

#pragma unroll
  for (int m = 0; m < 4; ++m) {
#pragma unroll
    for (int n = 0; n < 4; ++n) {
#pragma unroll
      for (int r = 0; r < 4; ++r) {
        int row = bm * 128 + wr * 64 + m * 16 + g * 4 + r;
        int col = bn * 128 + wc * 64 + n * 16 + c;
        if constexpr (OF32)
          ((float*)Cv)[(size_t)row * N + col] = acc[m][n][r];
        else
          ((unsigned short*)Cv)[(size_t)row * N + col] = f2bf(acc[m][n][r]);
      }
    }
  }
}

// ---------------- causal GQA flash attention ----------------
// Q: (B,NH,S,64) bf16 pre-scaled; K: (B,NKV,S,64) bf16; Vt: (B,NKV,64,S) bf16.
// Out: attn (B,S,NH*64) bf16. Computes S^T = K*Q^T, O^T = V^T*P^T.
__global__ __launch_bounds__(256) void attn_kernel(const unsigned short* __restrict__ Q,
                                                   const unsigned short* __restrict__ K,
                                                   const unsigned short* __restrict__ Vt,
                                                   unsigned short* __restrict__ attnOut) {
  __shared__ unsigned short lQ[64 * 72]; // [64][64] pad->72 (stride 144B)
  __shared__ unsigned short lK[32 * 72];
  __shared__ unsigned short lV[64 * 40]; // [64 d][32 kv] pad->40 (stride 80B)

  int bx = blockIdx.x;
  int qb = bx & 31;
  int h = (bx >> 5) & 31;
  int b = bx >> 10;
  int kvh = h >> 2;
  const unsigned short* Qp = Q + ((size_t)(b * NH_ + h) * S_ + qb * 64) * HD_;
  const unsigned short* Kp = K + (size_t)(b * NKV_ + kvh) * S_ * HD_;
  const unsigned short* Vp = Vt + (size_t)(b * NKV_ + kvh) * HD_ * S_;

  int t = threadIdx.x;
  // stage Q (64 rows x 64)
  {
    int part = t & 7, rr = t >> 3;
#pragma unroll
    for (int p = 0; p < 2; ++p) {
      int row = rr + p * 32;
      *(int4*)&lQ[row * 72 + part * 8] = *(const int4*)&Qp[(size_t)row * 64 + part * 8];
    }
  }

  int w = t >> 6, l = t & 63, g = l >> 4, c = l & 15;
  int q_global = qb * 64 + w * 16 + c;
  int wq_max = qb * 64 + w * 16 + 15;

  f32x4 o[4];
#pragma unroll
  for (int dt = 0; dt < 4; ++dt) o[dt] = 0.f;
  float mrun = -1e38f, lrun = 0.f;

  int nt = 2 * qb + 2;
  for (int tI = 0; tI < nt; ++tI) {
    int kv0 = tI * 32;
    __syncthreads();
    { // stage K tile (32 x 64)
      int part = t & 7, row = t >> 3;
      *(int4*)&lK[row * 72 + part * 8] = *(const int4*)&Kp[(size_t)(kv0 + row) * 64 + part * 8];
    }
    { // stage V tile (64 d x 32 kv)
      int part = t & 3, d = t >> 2;
      *(int4*)&lV[d * 40 + part * 8] = *(const int4*)&Vp[(size_t)d * S_ + kv0 + part * 8];
    }
    __syncthreads();

    if (kv0 <= wq_max) {
      short8 bq0 = *(const short8*)&lQ[(w * 16 + c) * 72 + g * 8];
      short8 bq1 = *(const short8*)&lQ[(w * 16 + c) * 72 + 32 + g * 8];
      f32x4 st[2];
#pragma unroll
      for (int mt = 0; mt < 2; ++mt) {
        short8 ak0 = *(const short8*)&lK[(mt * 16 + c) * 72 + g * 8];
        short8 ak1 = *(const short8*)&lK[(mt * 16 + c) * 72 + 32 + g * 8];
        f32x4 s = 0.f;
        s = __builtin_amdgcn_mfma_f32_16x16x32_bf16(ak0, bq0, s, 0, 0, 0);
        s = __builtin_amdgcn_mfma_f32_16x16x32_bf16(ak1, bq1, s, 0, 0, 0);
#pragma unroll
        for (int r = 0; r < 4; ++r) {
          int kvg = kv0 + mt * 16 + g * 4 + r;
          if (kvg > q_global) s[r] = -1e38f;
        }
        st[mt] = s;
      }
      // online softmax over kv (q = c is lane-resident)
      float pmax = st[0][0];
#pragma unroll
      for (int r = 1; r < 4; ++r) pmax = fmaxf(pmax, st[0][r]);
#pragma unroll
      for (int r = 0; r < 4; ++r) pmax = fmaxf(pmax, st[1][r]);
      pmax = fmaxf(pmax, __shfl_xor(pmax, 16, 64));
      pmax = fmaxf(pmax, __shfl_xor(pmax, 32, 64));
      float mnew = fmaxf(mrun, pmax);
      float sf = __expf(mrun - mnew);
      float pe[2][4];
      float rs = 0.f;
#pragma unroll
      for (int mt = 0; mt < 2; ++mt)
#pragma unroll
        for (int r = 0; r < 4; ++r) {
          pe[mt][r] = __expf(st[mt][r] - mnew);
          rs += pe[mt][r];
        }
      rs += __shfl_xor(rs, 16, 64);
      rs += __shfl_xor(rs, 32, 64);
      lrun = lrun * sf + rs;
      mrun = mnew;
#pragma unroll
      for (int dt = 0; dt < 4; ++dt)
#pragma unroll
        for (int r = 0; r < 4; ++r) o[dt][r] *= sf;

      // gather P^T as B-operand frag: lane (g,c) needs kv = 8g+j, q = c
      short8 pb;
#pragma unroll
      for (int j = 0; j < 8; ++j) {
        int src = (((g & 1) * 2 + (j >> 2)) << 4) + c;
        float v0 = __shfl(pe[0][j & 3], src, 64);
        float v1 = __shfl(pe[1][j & 3], src, 64);
        float pv = (g & 2) ? v1 : v0;
        pb[j] = (short)f2bf(pv);
      }
#pragma unroll
      for (int dt = 0; dt < 4; ++dt) {
        short8 av = *(const short8*)&lV[(dt * 16 + c) * 40 + g * 8];
        o[dt] = __builtin_amdgcn_mfma_f32_16x16x32_bf16(av, pb, o[dt], 0, 0, 0);
      }
    }
  }

  float inv = 1.f / lrun;
  size_t orow = ((size_t)(b * S_ + qb * 64 + w * 16 + c)) * (NH_ * HD_) + h * 64;
#pragma unroll
  for (int dt = 0; dt < 4; ++dt)
#pragma unroll
    for (int r = 0; r < 4; ++r)
      attnOut[orow + dt * 16 + g * 4 + r] = f2bf(o[dt][r] * inv);
}

extern "C" void kernel_launch(void* const* d_in, const int* in_sizes, int n_in,
                              void* d_out, int out_size, void* d_ws, size_t ws_size,
                              hipStream_t stream) {
  const float* hidden = (const float*)d_in[0];
  const float* bbox   = (const float*)d_in[1];
  const float* cosT   = (const float*)d_in[2];
  const float* sinT   = (const float*)d_in[3];
  const float* Wq  = (const float*)d_in[4];
  const float* Wk  = (const float*)d_in[5];
  const float* Wv  = (const float*)d_in[6];
  const float* Wo  = (const float*)d_in[7];
  const float* Wsq = (const float*)d_in[8];
  const float* Wsk = (const float*)d_in[9];

  char* ws = (char*)d_ws;
  size_t off = 0;
  auto alloc = [&](size_t bytes) {
    void* p = ws + off;
    off += (bytes + 255) & ~(size_t)255;
    return p;
  };
  unsigned short* WhT = (unsigned short*)alloc((size_t)3072 * 2048 * 2);
  unsigned short* WbT = (unsigned short*)alloc((size_t)2560 * 2048 * 2);
  unsigned short* WoT = (unsigned short*)alloc((size_t)2048 * 2048 * 2);
  unsigned short* P1  = (unsigned short*)alloc((size_t)4096 * 3072 * 2);
  unsigned short* P2  = (unsigned short*)alloc((size_t)4096 * 2560 * 2);
  unsigned short* Qb  = (unsigned short*)alloc((size_t)B_ * NH_ * S_ * HD_ * 2);
  unsigned short* Kb  = (unsigned short*)alloc((size_t)B_ * NKV_ * S_ * HD_ * 2);
  unsigned short* Vt  = (unsigned short*)alloc((size_t)B_ * NKV_ * HD_ * S_ * 2);
  unsigned short* attn = P1; // alias: P1 is dead after combine_rope + vtrans

  dim3 blk(256);
  // weight transpose+cast (concatenated N-major)
  transpose_cast<<<dim3(64, 64), blk, 0, stream>>>(Wq,  WhT, 2048, 2048);
  transpose_cast<<<dim3(16, 64), blk, 0, stream>>>(Wk,  WhT + (size_t)2048 * 2048, 512, 2048);
  transpose_cast<<<dim3(16, 64), blk, 0, stream>>>(Wv,  WhT + (size_t)2560 * 2048, 512, 2048);
  transpose_cast<<<dim3(64, 64), blk, 0, stream>>>(Wsq, WbT, 2048, 2048);
  transpose_cast<<<dim3(16, 64), blk, 0, stream>>>(Wsk, WbT + (size_t)2048 * 2048, 512, 2048);
  transpose_cast<<<dim3(64, 64), blk, 0, stream>>>(Wo,  WoT, 2048, 2048);

  // projections
  gemm128<1, 0><<<dim3(24, 32), blk, 0, stream>>>(hidden, WhT, P1, 4096, 3072, 2048);
  gemm128<1, 0><<<dim3(20, 32), blk, 0, stream>>>(bbox,   WbT, P2, 4096, 2560, 2048);

  // rope combine + V transpose
  combine_rope<<<dim3((B_ * S_ * 640) / 256), blk, 0, stream>>>(P1, P2, cosT, sinT, Qb, Kb);
  vtrans_kernel<<<dim3(64, 2, 16), blk, 0, stream>>>(P1, Vt);

  // attention
  attn_kernel<<<dim3(B_ * NH_ * (S_ / 64)), blk, 0, stream>>>(Qb, Kb, Vt, attn);

  // output projection (f32 out)
  gemm128<0, 1><<<dim3(16, 32), blk, 0, stream>>>(attn, WoT, d_out, 4096, 2048, 2048);
}

// Round 2
// 375.579 us; speedup vs baseline: 1.3272x; 1.3272x over previous
//
#include <hip/hip_runtime.h>

#define B_ 2
#define S_ 2048
#define H_ 2048
#define NH_ 32
#define NKV_ 8
#define HD_ 64

typedef short short8 __attribute__((ext_vector_type(8)));
typedef float f32x4 __attribute__((ext_vector_type(4)));
typedef float f32x16 __attribute__((ext_vector_type(16)));
typedef unsigned int uint4v __attribute__((ext_vector_type(4)));

__device__ __forceinline__ float bf2f(unsigned short u) {
  union { unsigned int i; float f; } v; v.i = ((unsigned int)u) << 16; return v.f;
}
__device__ __forceinline__ unsigned short f2bf(float f) {
  union { float f; unsigned int i; } v; v.f = f;
  unsigned int u = v.i;
  u += 0x7fffu + ((u >> 16) & 1u);
  return (unsigned short)(u >> 16);
}
__device__ __forceinline__ unsigned int cvtpk(float lo, float hi) {
  unsigned int r;
  asm("v_cvt_pk_bf16_f32 %0, %1, %2" : "=v"(r) : "v"(lo), "v"(hi));
  return r;
}
__device__ __forceinline__ void pl32swap(unsigned int& a, unsigned int& b) {
  asm("v_permlane32_swap_b32 %0, %1" : "+v"(a), "+v"(b));
}
__device__ __forceinline__ short8 mkfrag(unsigned a, unsigned b, unsigned c, unsigned d) {
  union { uint4v u; short8 s; } x;
  x.u = (uint4v){a, b, c, d};
  return x.s;
}
#define MFMA32(A, B, C) __builtin_amdgcn_mfma_f32_32x32x16_bf16(A, B, C, 0, 0, 0)

// ---------------- weight transpose + cast: W[K][N] f32 -> Wt[N][K] bf16 ----------------
__global__ __launch_bounds__(256) void transpose_cast(const float* __restrict__ W,
                                                      unsigned short* __restrict__ Wt,
                                                      int N, int K) {
  __shared__ float tile[32][33];
  int n0 = blockIdx.x * 32, k0 = blockIdx.y * 32;
  int tx = threadIdx.x & 31;
  int ty = threadIdx.x >> 5; // 0..7
#pragma unroll
  for (int i = 0; i < 32; i += 8)
    tile[ty + i][tx] = W[(size_t)(k0 + ty + i) * N + n0 + tx];
  __syncthreads();
#pragma unroll
  for (int i = 0; i < 32; i += 8)
    Wt[(size_t)(n0 + ty + i) * K + k0 + tx] = f2bf(tile[tx][ty + i]);
}

// ---------------- V transpose: P1 v-region (b,s | kv,d) -> Vt[b][kv][d][s] ----------------
__global__ __launch_bounds__(256) void vtrans_kernel(const unsigned short* __restrict__ P1,
                                                     unsigned short* __restrict__ Vt) {
  // grid: (S/32, HD/32, B*NKV)
  __shared__ unsigned short tile[32][33];
  int s0 = blockIdx.x * 32, d0 = blockIdx.y * 32, bk = blockIdx.z;
  int b = bk >> 3, kv = bk & 7;
  int tx = threadIdx.x & 31, ty = threadIdx.x >> 5;
#pragma unroll
  for (int i = 0; i < 32; i += 8)
    tile[ty + i][tx] = P1[(size_t)(b * S_ + s0 + ty + i) * 3072 + 2560 + kv * 64 + d0 + tx];
  __syncthreads();
#pragma unroll
  for (int i = 0; i < 32; i += 8)
    Vt[(size_t)(bk * 64 + d0 + ty + i) * S_ + s0 + tx] = tile[tx][ty + i];
}

// ---------------- RoPE combine: Q = rope(P1q+P2q)*SCALE, K = rope(P1k+P2k) ----------------
__global__ __launch_bounds__(256) void combine_rope(const unsigned short* __restrict__ P1,
                                                    const unsigned short* __restrict__ P2,
                                                    const float* __restrict__ cosT,
                                                    const float* __restrict__ sinT,
                                                    unsigned short* __restrict__ Qb,
                                                    unsigned short* __restrict__ Kb) {
  int id = blockIdx.x * 256 + threadIdx.x;   // total B*S*640
  int row = id / 640;                        // b*S + s
  int grp = id - row * 640;
  int b = row >> 11;
  int s = row & 2047;
  bool isQ = grp < 512;
  int n = isQ ? grp * 4 : (grp - 512) * 4;
  int h = n >> 6;
  int d = n & 63;
  int base = isQ ? 0 : 2048;
  const int ld1 = 3072, ld2 = 2560;
  int pd = (d < 32) ? d + 32 : d - 32;
  float sign = (d < 32) ? -1.f : 1.f;
  int pcol = base + h * 64 + pd;

  ushort4 a1 = *(const ushort4*)&P1[(size_t)row * ld1 + base + n];
  ushort4 a2 = *(const ushort4*)&P2[(size_t)row * ld2 + base + n];
  ushort4 b1 = *(const ushort4*)&P1[(size_t)row * ld1 + pcol];
  ushort4 b2 = *(const ushort4*)&P2[(size_t)row * ld2 + pcol];
  float4 cv = *(const float4*)&cosT[(size_t)row * 64 + d];
  float4 sv = *(const float4*)&sinT[(size_t)row * 64 + d];
  float scale = isQ ? 0.125f : 1.0f;

  float xs[4] = { bf2f(a1.x) + bf2f(a2.x), bf2f(a1.y) + bf2f(a2.y),
                  bf2f(a1.z) + bf2f(a2.z), bf2f(a1.w) + bf2f(a2.w) };
  float xp[4] = { bf2f(b1.x) + bf2f(b2.x), bf2f(b1.y) + bf2f(b2.y),
                  bf2f(b1.z) + bf2f(b2.z), bf2f(b1.w) + bf2f(b2.w) };
  float cc[4] = { cv.x, cv.y, cv.z, cv.w };
  float ss[4] = { sv.x, sv.y, sv.z, sv.w };
  ushort4 o;
  unsigned short* op = (unsigned short*)&o;
#pragma unroll
  for (int i = 0; i < 4; ++i)
    op[i] = f2bf((xs[i] * cc[i] + sign * xp[i] * ss[i]) * scale);

  if (isQ)
    *(ushort4*)&Qb[((size_t)(b * NH_ + h) * S_ + s) * HD_ + d] = o;
  else
    *(ushort4*)&Kb[((size_t)(b * NKV_ + h) * S_ + s) * HD_ + d] = o;
}

// ---------------- 128x128 GEMM: C[M][N] = A[M][K] * Bt[N][K]^T ----------------
template <int AF32, int OF32>
__global__ __launch_bounds__(256) void gemm128(const void* __restrict__ Av,
                                               const unsigned short* __restrict__ Bt,
                                               void* __restrict__ Cv,
                                               int M, int N, int K) {
  __shared__ unsigned short lA[128 * 40]; // [128][32] padded to 40 (stride 80B)
  __shared__ unsigned short lB[128 * 40];
  int bn = blockIdx.x, bm = blockIdx.y;
  int t = threadIdx.x;
  int w = t >> 6, l = t & 63, g = l >> 4, c = l & 15;
  int wr = w >> 1, wc = w & 1;

  f32x4 acc[4][4];
#pragma unroll
  for (int m = 0; m < 4; ++m)
#pragma unroll
    for (int n = 0; n < 4; ++n) acc[m][n] = 0.f;

  for (int k0 = 0; k0 < K; k0 += 32) {
    __syncthreads();
    if constexpr (AF32) {
      const float* Af = (const float*)Av;
#pragma unroll
      for (int p = 0; p < 4; ++p) {
        int f = p * 256 + t;
        int row = f >> 3, seg = f & 7;
        float4 v = *(const float4*)(Af + (size_t)(bm * 128 + row) * K + k0 + seg * 4);
        ushort4 ov;
        ov.x = f2bf(v.x); ov.y = f2bf(v.y); ov.z = f2bf(v.z); ov.w = f2bf(v.w);
        *(ushort4*)&lA[row * 40 + seg * 4] = ov;
      }
    } else {
      const unsigned short* Ab = (const unsigned short*)Av;
#pragma unroll
      for (int p = 0; p < 2; ++p) {
        int f = p * 256 + t;
        int row = f >> 2, seg = f & 3;
        *(int4*)&lA[row * 40 + seg * 8] =
            *(const int4*)(Ab + (size_t)(bm * 128 + row) * K + k0 + seg * 8);
      }
    }
#pragma unroll
    for (int p = 0; p < 2; ++p) {
      int f = p * 256 + t;
      int row = f >> 2, seg = f & 3;
      *(int4*)&lB[row * 40 + seg * 8] =
          *(const int4*)(Bt + (size_t)(bn * 128 + row) * K + k0 + seg * 8);
    }
    __syncthreads();

    short8 a[4], bfr[4];
#pragma unroll
    for (int m = 0; m < 4; ++m)
      a[m] = *(const short8*)&lA[(wr * 64 + m * 16 + c) * 40 + g * 8];
#pragma unroll
    for (int n = 0; n < 4; ++n)
      bfr[n] = *(const short8*)&lB[(wc * 64 + n * 16 + c) * 40 + g * 8];
#pragma unroll
    for (int m = 0; m < 4; ++m)
#pragma unroll
      for (int n = 0; n < 4; ++n)
        acc[m][n] = __builtin_amdgcn_mfma_f32_16x16x32_bf16(a[m], bfr[n], acc[m][n], 0, 0, 0);
  }

#pragma unroll
  for (int m = 0; m < 4; ++m) {
#pragma unroll
    for (int n = 0; n < 4; ++n) {
#pragma unroll
      for (int r = 0; r < 4; ++r) {
        int row = bm * 128 + wr * 64 + m * 16 + g * 4 + r;
        int col = bn * 128 + wc * 64 + n * 16 + c;
        if constexpr (OF32)
          ((float*)Cv)[(size_t)row * N + col] = acc[m][n][r];
        else
          ((unsigned short*)Cv)[(size_t)row * N + col] = f2bf(acc[m][n][r]);
      }
    }
  }
}

// ---------------- causal GQA flash attention, 8-warp 32x32 structure ----------------
// Q: (B,NH,S,64) bf16 pre-scaled; K: (B,NKV,S,64) bf16; Vt: (B,NKV,64,S) bf16.
// Out: attn (B,S,NH*64) bf16.
// Per warp: 32 q rows. Swapped QK^T: S^T[kv][q] = mfma(A=K, B=Q) so q = lane&31.
// C-layout (verified m74/m101): col = lane&31, row = (r&3) + 8*(r>>2) + 4*(lane>>5).
__global__ __launch_bounds__(512) void attn_kernel(const unsigned short* __restrict__ Q,
                                                   const unsigned short* __restrict__ K,
                                                   const unsigned short* __restrict__ Vt,
                                                   unsigned short* __restrict__ attnOut) {
  __shared__ unsigned short lK[2][64 * 64]; // [64 kv][64 d], 16B slots XOR-swizzled by (row&7)
  __shared__ unsigned short lV[2][64 * 64]; // [64 d][64 kv], same swizzle

  int bx = blockIdx.x;
  int qb = bx & 7;            // S/256 = 8 q-blocks
  int head = (bx >> 3) & 31;
  int b = bx >> 8;
  int kvh = head >> 2;
  const unsigned short* Qp = Q + ((size_t)(b * NH_ + head) * S_ + qb * 256) * HD_;
  const unsigned short* Kp = K + (size_t)(b * NKV_ + kvh) * S_ * HD_;
  const unsigned short* Vp = Vt + (size_t)(b * NKV_ + kvh) * HD_ * S_;

  int t = threadIdx.x;
  int w = t >> 6, l = t & 63;
  int q32 = l & 31, hf = l >> 5;
  int qbase_w = qb * 256 + w * 32;

  // Q fragments: lane needs Q[q=q32][d = kc*16 + 8*hf + j]
  short8 qf[4];
  {
    const unsigned short* qrow = Qp + (size_t)(w * 32 + q32) * HD_ + hf * 8;
#pragma unroll
    for (int kc = 0; kc < 4; ++kc)
      qf[kc] = *(const short8*)(qrow + kc * 16);
  }

  // staging geometry: 512 threads x 16B = 8KB = one 64x128B tile
  int srow = t >> 3;       // 0..63
  int sslot = t & 7;       // 0..7
  unsigned lOff = srow * 128 + ((sslot ^ (srow & 7)) << 4);
  const char* gK0 = (const char*)(Kp + (size_t)srow * 64 + sslot * 8);
  const char* gV0 = (const char*)(Vp + (size_t)srow * 2048 + sslot * 8);

  // prologue: stage tile 0 into buf 0
  {
    int4 rk = *(const int4*)(gK0);
    int4 rv = *(const int4*)(gV0);
    *(int4*)((char*)lK[0] + lOff) = rk;
    *(int4*)((char*)lV[0] + lOff) = rv;
  }
  __syncthreads();

  f32x16 oA = 0.f, oB = 0.f;  // O[q=crow][d=q32 (+32 for oB)]
  float mrun = -1e30f, lrun = 0.f;

  int nt = qb * 4 + 4;
  int cur = 0;
  for (int tI = 0; tI < nt; ++tI) {
    int kv0 = tI * 64;
    bool pf = (tI + 1 < nt);
    int4 nk, nv;
    if (pf) {
      nk = *(const int4*)(gK0 + (size_t)(kv0 + 64) * 128);
      nv = *(const int4*)(gV0 + (size_t)(kv0 + 64) * 2);
    }

    if (kv0 <= qbase_w + 31) {
      const char* lKc = (const char*)lK[cur];
      const char* lVc = (const char*)lV[cur];
      int swz = q32 & 7;

      // ---- QK^T: sA covers kv0..kv0+31, sB covers kv0+32..kv0+63 ----
      f32x16 sA = 0.f, sB = 0.f;
#pragma unroll
      for (int kc = 0; kc < 4; ++kc) {
        int cs = (kc << 1) | hf;
        short8 ak0 = *(const short8*)(lKc + q32 * 128 + ((cs ^ swz) << 4));
        short8 ak1 = *(const short8*)(lKc + (32 + q32) * 128 + ((cs ^ swz) << 4));
        sA = MFMA32(ak0, qf[kc], sA);
        sB = MFMA32(ak1, qf[kc], sB);
      }

      // ---- causal mask (only on partial tiles) ----
      if (kv0 + 63 > qbase_w) {
        int qg = qbase_w + q32;
#pragma unroll
        for (int r = 0; r < 16; ++r) {
          int kvr = kv0 + (r & 3) + ((r >> 2) << 3) + (hf << 2);
          if (kvr > qg) sA[r] = -1e30f;
          if (kvr + 32 > qg) sB[r] = -1e30f;
        }
      }

      // ---- online softmax (q = q32 is lane-resident) ----
      float pmax = sA[0];
#pragma unroll
      for (int r = 1; r < 16; ++r) pmax = fmaxf(pmax, sA[r]);
#pragma unroll
      for (int r = 0; r < 16; ++r) pmax = fmaxf(pmax, sB[r]);
      pmax = fmaxf(pmax, __shfl_xor(pmax, 32, 64));

      // defer-max (T13): rescale only when the running max grows by > 8
      if (!__all(pmax <= mrun + 8.f)) {
        float mnew = fmaxf(mrun, pmax);
        float sf = __expf(mrun - mnew);
        lrun *= sf;
        mrun = mnew;
        // O's q index is crow(r,hf); fetch that q's sf
#pragma unroll
        for (int r = 0; r < 16; ++r) {
          int src = (r & 3) + ((r >> 2) << 3) + (hf << 2);
          float sfr = __shfl(sf, src, 64);
          oA[r] *= sfr;
          oB[r] *= sfr;
        }
      }

      // ---- P = exp(S - m), row sum ----
      float rs = 0.f;
#pragma unroll
      for (int r = 0; r < 16; ++r) { sA[r] = __expf(sA[r] - mrun); rs += sA[r]; }
#pragma unroll
      for (int r = 0; r < 16; ++r) { sB[r] = __expf(sB[r] - mrun); rs += sB[r]; }
      rs += __shfl_xor(rs, 32, 64);
      lrun += rs;

      // ---- P -> bf16 A-fragments via cvt_pk + permlane32_swap (T12) ----
      short8 paf[4];
      {
        unsigned c0 = cvtpk(sA[0], sA[1]), c1 = cvtpk(sA[2], sA[3]);
        unsigned c2 = cvtpk(sA[4], sA[5]), c3 = cvtpk(sA[6], sA[7]);
        pl32swap(c0, c2); pl32swap(c1, c3);
        paf[0] = mkfrag(c0, c1, c2, c3);
      }
      {
        unsigned c0 = cvtpk(sA[8], sA[9]),  c1 = cvtpk(sA[10], sA[11]);
        unsigned c2 = cvtpk(sA[12], sA[13]), c3 = cvtpk(sA[14], sA[15]);
        pl32swap(c0, c2); pl32swap(c1, c3);
        paf[1] = mkfrag(c0, c1, c2, c3);
      }
      {
        unsigned c0 = cvtpk(sB[0], sB[1]), c1 = cvtpk(sB[2], sB[3]);
        unsigned c2 = cvtpk(sB[4], sB[5]), c3 = cvtpk(sB[6], sB[7]);
        pl32swap(c0, c2); pl32swap(c1, c3);
        paf[2] = mkfrag(c0, c1, c2, c3);
      }
      {
        unsigned c0 = cvtpk(sB[8], sB[9]),  c1 = cvtpk(sB[10], sB[11]);
        unsigned c2 = cvtpk(sB[12], sB[13]), c3 = cvtpk(sB[14], sB[15]);
        pl32swap(c0, c2); pl32swap(c1, c3);
        paf[3] = mkfrag(c0, c1, c2, c3);
      }

      // ---- PV: O += P * V ----
#pragma unroll
      for (int ks = 0; ks < 4; ++ks) {
        int cs = (ks << 1) | hf;
        short8 v0 = *(const short8*)(lVc + q32 * 128 + ((cs ^ swz) << 4));
        short8 v1 = *(const short8*)(lVc + (32 + q32) * 128 + ((cs ^ swz) << 4));
        oA = MFMA32(paf[ks], v0, oA);
        oB = MFMA32(paf[ks], v1, oB);
      }
    }

    if (pf) {
      *(int4*)((char*)lK[cur ^ 1] + lOff) = nk;
      *(int4*)((char*)lV[cur ^ 1] + lOff) = nv;
    }
    __syncthreads();
    cur ^= 1;
  }

  // ---- epilogue: O / lrun, write out ----
  float linv = 1.f / lrun;
#pragma unroll
  for (int r = 0; r < 16; ++r) {
    int src = (r & 3) + ((r >> 2) << 3) + (hf << 2);   // q = crow(r,hf)
    float li = __shfl(linv, src, 64);
    unsigned short* op = attnOut + ((size_t)(b * S_ + qbase_w + src)) * (NH_ * HD_) + head * 64;
    op[q32] = f2bf(oA[r] * li);
    op[32 + q32] = f2bf(oB[r] * li);
  }
}

extern "C" void kernel_launch(void* const* d_in, const int* in_sizes, int n_in,
                              void* d_out, int out_size, void* d_ws, size_t ws_size,
                              hipStream_t stream) {
  const float* hidden = (const float*)d_in[0];
  const float* bbox   = (const float*)d_in[1];
  const float* cosT   = (const float*)d_in[2];
  const float* sinT   = (const float*)d_in[3];
  const float* Wq  = (const float*)d_in[4];
  const float* Wk  = (const float*)d_in[5];
  const float* Wv  = (const float*)d_in[6];
  const float* Wo  = (const float*)d_in[7];
  const float* Wsq = (const float*)d_in[8];
  const float* Wsk = (const float*)d_in[9];

  char* ws = (char*)d_ws;
  size_t off = 0;
  auto alloc = [&](size_t bytes) {
    void* p = ws + off;
    off += (bytes + 255) & ~(size_t)255;
    return p;
  };
  unsigned short* WhT = (unsigned short*)alloc((size_t)3072 * 2048 * 2);
  unsigned short* WbT = (unsigned short*)alloc((size_t)2560 * 2048 * 2);
  unsigned short* WoT = (unsigned short*)alloc((size_t)2048 * 2048 * 2);
  unsigned short* P1  = (unsigned short*)alloc((size_t)4096 * 3072 * 2);
  unsigned short* P2  = (unsigned short*)alloc((size_t)4096 * 2560 * 2);
  unsigned short* Qb  = (unsigned short*)alloc((size_t)B_ * NH_ * S_ * HD_ * 2);
  unsigned short* Kb  = (unsigned short*)alloc((size_t)B_ * NKV_ * S_ * HD_ * 2);
  unsigned short* Vt  = (unsigned short*)alloc((size_t)B_ * NKV_ * HD_ * S_ * 2);
  unsigned short* attn = P1; // alias: P1 is dead after combine_rope + vtrans

  dim3 blk(256);
  transpose_cast<<<dim3(64, 64), blk, 0, stream>>>(Wq,  WhT, 2048, 2048);
  transpose_cast<<<dim3(16, 64), blk, 0, stream>>>(Wk,  WhT + (size_t)2048 * 2048, 512, 2048);
  transpose_cast<<<dim3(16, 64), blk, 0, stream>>>(Wv,  WhT + (size_t)2560 * 2048, 512, 2048);
  transpose_cast<<<dim3(64, 64), blk, 0, stream>>>(Wsq, WbT, 2048, 2048);
  transpose_cast<<<dim3(16, 64), blk, 0, stream>>>(Wsk, WbT + (size_t)2048 * 2048, 512, 2048);
  transpose_cast<<<dim3(64, 64), blk, 0, stream>>>(Wo,  WoT, 2048, 2048);

  gemm128<1, 0><<<dim3(24, 32), blk, 0, stream>>>(hidden, WhT, P1, 4096, 3072, 2048);
  gemm128<1, 0><<<dim3(20, 32), blk, 0, stream>>>(bbox,   WbT, P2, 4096, 2560, 2048);

  combine_rope<<<dim3((B_ * S_ * 640) / 256), blk, 0, stream>>>(P1, P2, cosT, sinT, Qb, Kb);
  vtrans_kernel<<<dim3(64, 2, 16), blk, 0, stream>>>(P1, Vt);

  attn_kernel<<<dim3(512), dim3(512), 0, stream>>>(Qb, Kb, Vt, attn);

  gemm128<0, 1><<<dim3(16, 32), blk, 0, stream>>>(attn, WoT, d_out, 4096, 2048, 2048);
}

// Round 3
// 334.544 us; speedup vs baseline: 1.4900x; 1.1227x over previous
//
#include <hip/hip_runtime.h>

#define B_ 2
#define S_ 2048
#define H_ 2048
#define NH_ 32
#define NKV_ 8
#define HD_ 64

typedef short short8 __attribute__((ext_vector_type(8)));
typedef float f32x4 __attribute__((ext_vector_type(4)));
typedef float f32x16 __attribute__((ext_vector_type(16)));
typedef unsigned int uint4v __attribute__((ext_vector_type(4)));

__device__ __forceinline__ float bf2f(unsigned short u) {
  union { unsigned int i; float f; } v; v.i = ((unsigned int)u) << 16; return v.f;
}
__device__ __forceinline__ unsigned short f2bf(float f) {
  union { float f; unsigned int i; } v; v.f = f;
  unsigned int u = v.i;
  u += 0x7fffu + ((u >> 16) & 1u);
  return (unsigned short)(u >> 16);
}
__device__ __forceinline__ unsigned int cvtpk(float lo, float hi) {
  unsigned int r;
  asm("v_cvt_pk_bf16_f32 %0, %1, %2" : "=v"(r) : "v"(lo), "v"(hi));
  return r;
}
__device__ __forceinline__ void pl32swap(unsigned int& a, unsigned int& b) {
  asm("v_permlane32_swap_b32 %0, %1" : "+v"(a), "+v"(b));
}
__device__ __forceinline__ short8 mkfrag(unsigned a, unsigned b, unsigned c, unsigned d) {
  union { uint4v u; short8 s; } x;
  x.u = (uint4v){a, b, c, d};
  return x.s;
}
__device__ __forceinline__ void gload_lds16(const unsigned short* g, unsigned short* l) {
  __builtin_amdgcn_global_load_lds((const __attribute__((address_space(1))) void*)g,
                                   (__attribute__((address_space(3))) void*)l,
                                   16, 0, 0);
}
#define MFMA32(A, B, C) __builtin_amdgcn_mfma_f32_32x32x16_bf16(A, B, C, 0, 0, 0)

// ---------------- cast f32 -> bf16, 8 elems/thread ----------------
__global__ __launch_bounds__(256) void cast_f32_bf16(const float* __restrict__ in,
                                                     unsigned short* __restrict__ out,
                                                     int n8) {
  int i = blockIdx.x * 256 + threadIdx.x;
  if (i >= n8) return;
  float4 v0 = ((const float4*)in)[i * 2];
  float4 v1 = ((const float4*)in)[i * 2 + 1];
  ushort4 o0, o1;
  o0.x = f2bf(v0.x); o0.y = f2bf(v0.y); o0.z = f2bf(v0.z); o0.w = f2bf(v0.w);
  o1.x = f2bf(v1.x); o1.y = f2bf(v1.y); o1.z = f2bf(v1.z); o1.w = f2bf(v1.w);
  ((ushort4*)out)[i * 2] = o0;
  ((ushort4*)out)[i * 2 + 1] = o1;
}

// ---------------- weight transpose + cast: W[K][N] f32 -> Wt[N][K] bf16 ----------------
__global__ __launch_bounds__(256) void transpose_cast(const float* __restrict__ W,
                                                      unsigned short* __restrict__ Wt,
                                                      int N, int K) {
  __shared__ float tile[32][33];
  int n0 = blockIdx.x * 32, k0 = blockIdx.y * 32;
  int tx = threadIdx.x & 31;
  int ty = threadIdx.x >> 5; // 0..7
#pragma unroll
  for (int i = 0; i < 32; i += 8)
    tile[ty + i][tx] = W[(size_t)(k0 + ty + i) * N + n0 + tx];
  __syncthreads();
#pragma unroll
  for (int i = 0; i < 32; i += 8)
    Wt[(size_t)(n0 + ty + i) * K + k0 + tx] = f2bf(tile[tx][ty + i]);
}

// ---------------- V transpose: P1 v-region (b,s | kv,d) -> Vt[b][kv][d][s] ----------------
__global__ __launch_bounds__(256) void vtrans_kernel(const unsigned short* __restrict__ P1,
                                                     unsigned short* __restrict__ Vt) {
  // grid: (S/32, HD/32, B*NKV)
  __shared__ unsigned short tile[32][33];
  int s0 = blockIdx.x * 32, d0 = blockIdx.y * 32, bk = blockIdx.z;
  int b = bk >> 3, kv = bk & 7;
  int tx = threadIdx.x & 31, ty = threadIdx.x >> 5;
#pragma unroll
  for (int i = 0; i < 32; i += 8)
    tile[ty + i][tx] = P1[(size_t)(b * S_ + s0 + ty + i) * 3072 + 2560 + kv * 64 + d0 + tx];
  __syncthreads();
#pragma unroll
  for (int i = 0; i < 32; i += 8)
    Vt[(size_t)(bk * 64 + d0 + ty + i) * S_ + s0 + tx] = tile[tx][ty + i];
}

// ---------------- RoPE combine: Q = rope(P1q+P2q)*SCALE, K = rope(P1k+P2k) ----------------
__global__ __launch_bounds__(256) void combine_rope(const unsigned short* __restrict__ P1,
                                                    const unsigned short* __restrict__ P2,
                                                    const float* __restrict__ cosT,
                                                    const float* __restrict__ sinT,
                                                    unsigned short* __restrict__ Qb,
                                                    unsigned short* __restrict__ Kb) {
  int id = blockIdx.x * 256 + threadIdx.x;   // total B*S*640
  int row = id / 640;                        // b*S + s
  int grp = id - row * 640;
  int b = row >> 11;
  int s = row & 2047;
  bool isQ = grp < 512;
  int n = isQ ? grp * 4 : (grp - 512) * 4;
  int h = n >> 6;
  int d = n & 63;
  int base = isQ ? 0 : 2048;
  const int ld1 = 3072, ld2 = 2560;
  int pd = (d < 32) ? d + 32 : d - 32;
  float sign = (d < 32) ? -1.f : 1.f;
  int pcol = base + h * 64 + pd;

  ushort4 a1 = *(const ushort4*)&P1[(size_t)row * ld1 + base + n];
  ushort4 a2 = *(const ushort4*)&P2[(size_t)row * ld2 + base + n];
  ushort4 b1 = *(const ushort4*)&P1[(size_t)row * ld1 + pcol];
  ushort4 b2 = *(const ushort4*)&P2[(size_t)row * ld2 + pcol];
  float4 cv = *(const float4*)&cosT[(size_t)row * 64 + d];
  float4 sv = *(const float4*)&sinT[(size_t)row * 64 + d];
  float scale = isQ ? 0.125f : 1.0f;

  float xs[4] = { bf2f(a1.x) + bf2f(a2.x), bf2f(a1.y) + bf2f(a2.y),
                  bf2f(a1.z) + bf2f(a2.z), bf2f(a1.w) + bf2f(a2.w) };
  float xp[4] = { bf2f(b1.x) + bf2f(b2.x), bf2f(b1.y) + bf2f(b2.y),
                  bf2f(b1.z) + bf2f(b2.z), bf2f(b1.w) + bf2f(b2.w) };
  float cc[4] = { cv.x, cv.y, cv.z, cv.w };
  float ss[4] = { sv.x, sv.y, sv.z, sv.w };
  ushort4 o;
  unsigned short* op = (unsigned short*)&o;
#pragma unroll
  for (int i = 0; i < 4; ++i)
    op[i] = f2bf((xs[i] * cc[i] + sign * xp[i] * ss[i]) * scale);

  if (isQ)
    *(ushort4*)&Qb[((size_t)(b * NH_ + h) * S_ + s) * HD_ + d] = o;
  else
    *(ushort4*)&Kb[((size_t)(b * NKV_ + h) * S_ + s) * HD_ + d] = o;
}

// ---------------- m97-structure GEMM: C[M][N] = A[M][K](bf16) * Bt[N][K]^T ----------------
// 128x128 tile, BK=32, 4 waves, global_load_lds width=16 staging, linear LDS.
template <int OF32>
__global__ __launch_bounds__(256) void gemm_bt(const unsigned short* __restrict__ A,
                                               const unsigned short* __restrict__ Bt,
                                               void* __restrict__ Cv,
                                               int N, int K, int nbx) {
  __shared__ unsigned short lA[128 * 32];
  __shared__ unsigned short lB[128 * 32];
  int nwg = gridDim.x;
  int orig = blockIdx.x;
  int wgid = (orig & 7) * (nwg >> 3) + (orig >> 3);  // bijective: nwg % 8 == 0
  int bn = wgid % nbx;
  int bm = wgid / nbx;
  int t = threadIdx.x;
  int w = t >> 6, l = t & 63, g = l >> 4, c = l & 15;
  int wr = w >> 1, wc = w & 1;

  // staging: issue p covers rows p*64 + w*16 + (l>>2), col bytes (l&3)*16
  int srow = w * 16 + (l >> 2);
  int scol = (l & 3) * 8;
  const unsigned short* gA0 = A + (size_t)(bm * 128 + srow) * K + scol;
  const unsigned short* gA1 = A + (size_t)(bm * 128 + 64 + srow) * K + scol;
  const unsigned short* gB0 = Bt + (size_t)(bn * 128 + srow) * K + scol;
  const unsigned short* gB1 = Bt + (size_t)(bn * 128 + 64 + srow) * K + scol;
  unsigned short* lA0 = &lA[w * 512];
  unsigned short* lA1 = &lA[2048 + w * 512];
  unsigned short* lB0 = &lB[w * 512];
  unsigned short* lB1 = &lB[2048 + w * 512];

  f32x4 acc[4][4];
#pragma unroll
  for (int m = 0; m < 4; ++m)
#pragma unroll
    for (int n = 0; n < 4; ++n) acc[m][n] = 0.f;

  for (int k0 = 0; k0 < K; k0 += 32) {
    __syncthreads();
    gload_lds16(gA0 + k0, lA0);
    gload_lds16(gA1 + k0, lA1);
    gload_lds16(gB0 + k0, lB0);
    gload_lds16(gB1 + k0, lB1);
    __syncthreads();

    short8 a[4], bfr[4];
#pragma unroll
    for (int m = 0; m < 4; ++m)
      a[m] = *(const short8*)&lA[(wr * 64 + m * 16 + c) * 32 + g * 8];
#pragma unroll
    for (int n = 0; n < 4; ++n)
      bfr[n] = *(const short8*)&lB[(wc * 64 + n * 16 + c) * 32 + g * 8];
#pragma unroll
    for (int m = 0; m < 4; ++m)
#pragma unroll
      for (int n = 0; n < 4; ++n)
        acc[m][n] = __builtin_amdgcn_mfma_f32_16x16x32_bf16(a[m], bfr[n], acc[m][n], 0, 0, 0);
  }

#pragma unroll
  for (int m = 0; m < 4; ++m) {
#pragma unroll
    for (int n = 0; n < 4; ++n) {
#pragma unroll
      for (int r = 0; r < 4; ++r) {
        int row = bm * 128 + wr * 64 + m * 16 + g * 4 + r;
        int col = bn * 128 + wc * 64 + n * 16 + c;
        if constexpr (OF32)
          ((float*)Cv)[(size_t)row * N + col] = acc[m][n][r];
        else
          ((unsigned short*)Cv)[(size_t)row * N + col] = f2bf(acc[m][n][r]);
      }
    }
  }
}

// ---------------- causal GQA flash attention, 8-warp 32x32 structure ----------------
__global__ __launch_bounds__(512) void attn_kernel(const unsigned short* __restrict__ Q,
                                                   const unsigned short* __restrict__ K,
                                                   const unsigned short* __restrict__ Vt,
                                                   unsigned short* __restrict__ attnOut) {
  __shared__ unsigned short lK[2][64 * 64]; // [64 kv][64 d], 16B slots XOR-swizzled by (row&7)
  __shared__ unsigned short lV[2][64 * 64]; // [64 d][64 kv], same swizzle

  int bx = blockIdx.x;
  int qb = bx & 7;            // S/256 = 8 q-blocks
  int head = (bx >> 3) & 31;
  int b = bx >> 8;
  int kvh = head >> 2;
  const unsigned short* Qp = Q + ((size_t)(b * NH_ + head) * S_ + qb * 256) * HD_;
  const unsigned short* Kp = K + (size_t)(b * NKV_ + kvh) * S_ * HD_;
  const unsigned short* Vp = Vt + (size_t)(b * NKV_ + kvh) * HD_ * S_;

  int t = threadIdx.x;
  int w = t >> 6, l = t & 63;
  int q32 = l & 31, hf = l >> 5;
  int qbase_w = qb * 256 + w * 32;

  short8 qf[4];
  {
    const unsigned short* qrow = Qp + (size_t)(w * 32 + q32) * HD_ + hf * 8;
#pragma unroll
    for (int kc = 0; kc < 4; ++kc)
      qf[kc] = *(const short8*)(qrow + kc * 16);
  }

  int srow = t >> 3;       // 0..63
  int sslot = t & 7;       // 0..7
  unsigned lOff = srow * 128 + ((sslot ^ (srow & 7)) << 4);
  const char* gK0 = (const char*)(Kp + (size_t)srow * 64 + sslot * 8);
  const char* gV0 = (const char*)(Vp + (size_t)srow * 2048 + sslot * 8);

  {
    int4 rk = *(const int4*)(gK0);
    int4 rv = *(const int4*)(gV0);
    *(int4*)((char*)lK[0] + lOff) = rk;
    *(int4*)((char*)lV[0] + lOff) = rv;
  }
  __syncthreads();

  f32x16 oA = 0.f, oB = 0.f;  // O[q=crow][d=q32 (+32 for oB)]
  float mrun = -1e30f, lrun = 0.f;

  int nt = qb * 4 + 4;
  int cur = 0;
  for (int tI = 0; tI < nt; ++tI) {
    int kv0 = tI * 64;
    bool pf = (tI + 1 < nt);
    int4 nk, nv;
    if (pf) {
      nk = *(const int4*)(gK0 + (size_t)(kv0 + 64) * 128);
      nv = *(const int4*)(gV0 + (size_t)(kv0 + 64) * 2);
    }

    if (kv0 <= qbase_w + 31) {
      const char* lKc = (const char*)lK[cur];
      const char* lVc = (const char*)lV[cur];
      int swz = q32 & 7;

      f32x16 sA = 0.f, sB = 0.f;
#pragma unroll
      for (int kc = 0; kc < 4; ++kc) {
        int cs = (kc << 1) | hf;
        short8 ak0 = *(const short8*)(lKc + q32 * 128 + ((cs ^ swz) << 4));
        short8 ak1 = *(const short8*)(lKc + (32 + q32) * 128 + ((cs ^ swz) << 4));
        sA = MFMA32(ak0, qf[kc], sA);
        sB = MFMA32(ak1, qf[kc], sB);
      }

      if (kv0 + 63 > qbase_w) {
        int qg = qbase_w + q32;
#pragma unroll
        for (int r = 0; r < 16; ++r) {
          int kvr = kv0 + (r & 3) + ((r >> 2) << 3) + (hf << 2);
          if (kvr > qg) sA[r] = -1e30f;
          if (kvr + 32 > qg) sB[r] = -1e30f;
        }
      }

      float pmax = sA[0];
#pragma unroll
      for (int r = 1; r < 16; ++r) pmax = fmaxf(pmax, sA[r]);
#pragma unroll
      for (int r = 0; r < 16; ++r) pmax = fmaxf(pmax, sB[r]);
      pmax = fmaxf(pmax, __shfl_xor(pmax, 32, 64));

      if (!__all(pmax <= mrun + 8.f)) {
        float mnew = fmaxf(mrun, pmax);
        float sf = __expf(mrun - mnew);
        lrun *= sf;
        mrun = mnew;
#pragma unroll
        for (int r = 0; r < 16; ++r) {
          int src = (r & 3) + ((r >> 2) << 3) + (hf << 2);
          float sfr = __shfl(sf, src, 64);
          oA[r] *= sfr;
          oB[r] *= sfr;
        }
      }

      float rs = 0.f;
#pragma unroll
      for (int r = 0; r < 16; ++r) { sA[r] = __expf(sA[r] - mrun); rs += sA[r]; }
#pragma unroll
      for (int r = 0; r < 16; ++r) { sB[r] = __expf(sB[r] - mrun); rs += sB[r]; }
      rs += __shfl_xor(rs, 32, 64);
      lrun += rs;

      short8 paf[4];
      {
        unsigned c0 = cvtpk(sA[0], sA[1]), c1 = cvtpk(sA[2], sA[3]);
        unsigned c2 = cvtpk(sA[4], sA[5]), c3 = cvtpk(sA[6], sA[7]);
        pl32swap(c0, c2); pl32swap(c1, c3);
        paf[0] = mkfrag(c0, c1, c2, c3);
      }
      {
        unsigned c0 = cvtpk(sA[8], sA[9]),  c1 = cvtpk(sA[10], sA[11]);
        unsigned c2 = cvtpk(sA[12], sA[13]), c3 = cvtpk(sA[14], sA[15]);
        pl32swap(c0, c2); pl32swap(c1, c3);
        paf[1] = mkfrag(c0, c1, c2, c3);
      }
      {
        unsigned c0 = cvtpk(sB[0], sB[1]), c1 = cvtpk(sB[2], sB[3]);
        unsigned c2 = cvtpk(sB[4], sB[5]), c3 = cvtpk(sB[6], sB[7]);
        pl32swap(c0, c2); pl32swap(c1, c3);
        paf[2] = mkfrag(c0, c1, c2, c3);
      }
      {
        unsigned c0 = cvtpk(sB[8], sB[9]),  c1 = cvtpk(sB[10], sB[11]);
        unsigned c2 = cvtpk(sB[12], sB[13]), c3 = cvtpk(sB[14], sB[15]);
        pl32swap(c0, c2); pl32swap(c1, c3);
        paf[3] = mkfrag(c0, c1, c2, c3);
      }

#pragma unroll
      for (int ks = 0; ks < 4; ++ks) {
        int cs = (ks << 1) | hf;
        short8 v0 = *(const short8*)(lVc + q32 * 128 + ((cs ^ swz) << 4));
        short8 v1 = *(const short8*)(lVc + (32 + q32) * 128 + ((cs ^ swz) << 4));
        oA = MFMA32(paf[ks], v0, oA);
        oB = MFMA32(paf[ks], v1, oB);
      }
    }

    if (pf) {
      *(int4*)((char*)lK[cur ^ 1] + lOff) = nk;
      *(int4*)((char*)lV[cur ^ 1] + lOff) = nv;
    }
    __syncthreads();
    cur ^= 1;
  }

  float linv = 1.f / lrun;
#pragma unroll
  for (int r = 0; r < 16; ++r) {
    int src = (r & 3) + ((r >> 2) << 3) + (hf << 2);   // q = crow(r,hf)
    float li = __shfl(linv, src, 64);
    unsigned short* op = attnOut + ((size_t)(b * S_ + qbase_w + src)) * (NH_ * HD_) + head * 64;
    op[q32] = f2bf(oA[r] * li);
    op[32 + q32] = f2bf(oB[r] * li);
  }
}

extern "C" void kernel_launch(void* const* d_in, const int* in_sizes, int n_in,
                              void* d_out, int out_size, void* d_ws, size_t ws_size,
                              hipStream_t stream) {
  const float* hidden = (const float*)d_in[0];
  const float* bbox   = (const float*)d_in[1];
  const float* cosT   = (const float*)d_in[2];
  const float* sinT   = (const float*)d_in[3];
  const float* Wq  = (const float*)d_in[4];
  const float* Wk  = (const float*)d_in[5];
  const float* Wv  = (const float*)d_in[6];
  const float* Wo  = (const float*)d_in[7];
  const float* Wsq = (const float*)d_in[8];
  const float* Wsk = (const float*)d_in[9];

  char* ws = (char*)d_ws;
  size_t off = 0;
  auto alloc = [&](size_t bytes) {
    void* p = ws + off;
    off += (bytes + 255) & ~(size_t)255;
    return p;
  };
  unsigned short* WhT = (unsigned short*)alloc((size_t)3072 * 2048 * 2);
  unsigned short* WbT = (unsigned short*)alloc((size_t)2560 * 2048 * 2);
  unsigned short* WoT = (unsigned short*)alloc((size_t)2048 * 2048 * 2);
  unsigned short* P1  = (unsigned short*)alloc((size_t)4096 * 3072 * 2);
  unsigned short* P2  = (unsigned short*)alloc((size_t)4096 * 2560 * 2);
  unsigned short* Xh  = (unsigned short*)alloc((size_t)4096 * 2048 * 2);
  unsigned short* Xb  = (unsigned short*)alloc((size_t)4096 * 2048 * 2);
  // aliases into dead regions:
  unsigned short* attn = Xh;             // Xh dead after P1 gemm; attn written after
  unsigned short* Qb   = Xb;             // Xb dead after P2 gemm
  unsigned short* Kb   = Xb + (size_t)B_ * NH_ * S_ * HD_;
  unsigned short* Vt   = Kb + (size_t)B_ * NKV_ * S_ * HD_;

  dim3 blk(256);
  // input casts f32 -> bf16
  cast_f32_bf16<<<dim3(4096), blk, 0, stream>>>(hidden, Xh, 4096 * 2048 / 8);
  cast_f32_bf16<<<dim3(4096), blk, 0, stream>>>(bbox,   Xb, 4096 * 2048 / 8);

  // weight transpose+cast (concatenated N-major)
  transpose_cast<<<dim3(64, 64), blk, 0, stream>>>(Wq,  WhT, 2048, 2048);
  transpose_cast<<<dim3(16, 64), blk, 0, stream>>>(Wk,  WhT + (size_t)2048 * 2048, 512, 2048);
  transpose_cast<<<dim3(16, 64), blk, 0, stream>>>(Wv,  WhT + (size_t)2560 * 2048, 512, 2048);
  transpose_cast<<<dim3(64, 64), blk, 0, stream>>>(Wsq, WbT, 2048, 2048);
  transpose_cast<<<dim3(16, 64), blk, 0, stream>>>(Wsk, WbT + (size_t)2048 * 2048, 512, 2048);
  transpose_cast<<<dim3(64, 64), blk, 0, stream>>>(Wo,  WoT, 2048, 2048);

  // projections (m97 structure): grids are (M/128)*(N/128), all % 8 == 0
  gemm_bt<0><<<dim3(32 * 24), blk, 0, stream>>>(Xh, WhT, P1, 3072, 2048, 24);
  gemm_bt<0><<<dim3(32 * 20), blk, 0, stream>>>(Xb, WbT, P2, 2560, 2048, 20);

  // rope combine + V transpose (write into Xb region — Xb dead now)
  combine_rope<<<dim3((B_ * S_ * 640) / 256), blk, 0, stream>>>(P1, P2, cosT, sinT, Qb, Kb);
  vtrans_kernel<<<dim3(64, 2, 16), blk, 0, stream>>>(P1, Vt);

  // attention (writes attn = Xh region — Xh dead now)
  attn_kernel<<<dim3(512), dim3(512), 0, stream>>>(Qb, Kb, Vt, attn);

  // output projection (f32 out)
  gemm_bt<1><<<dim3(32 * 16), blk, 0, stream>>>(attn, WoT, d_out, 2048, 2048, 16);
}

// Round 4
// 305.210 us; speedup vs baseline: 1.6332x; 1.0961x over previous
//
#include <hip/hip_runtime.h>

#define B_ 2
#define S_ 2048
#define H_ 2048
#define NH_ 32
#define NKV_ 8
#define HD_ 64

typedef short short8 __attribute__((ext_vector_type(8)));
typedef float f32x4 __attribute__((ext_vector_type(4)));
typedef float f32x16 __attribute__((ext_vector_type(16)));
typedef unsigned int uint4v __attribute__((ext_vector_type(4)));

__device__ __forceinline__ float bf2f(unsigned short u) {
  union { unsigned int i; float f; } v; v.i = ((unsigned int)u) << 16; return v.f;
}
__device__ __forceinline__ unsigned short f2bf(float f) {
  union { float f; unsigned int i; } v; v.f = f;
  unsigned int u = v.i;
  u += 0x7fffu + ((u >> 16) & 1u);
  return (unsigned short)(u >> 16);
}
__device__ __forceinline__ unsigned int cvtpk(float lo, float hi) {
  unsigned int r;
  asm("v_cvt_pk_bf16_f32 %0, %1, %2" : "=v"(r) : "v"(lo), "v"(hi));
  return r;
}
__device__ __forceinline__ void pl32swap(unsigned int& a, unsigned int& b) {
  asm("v_permlane32_swap_b32 %0, %1" : "+v"(a), "+v"(b));
}
__device__ __forceinline__ short8 mkfrag(unsigned a, unsigned b, unsigned c, unsigned d) {
  union { uint4v u; short8 s; } x;
  x.u = (uint4v){a, b, c, d};
  return x.s;
}
__device__ __forceinline__ void gload_lds16(const unsigned short* g, unsigned short* l) {
  __builtin_amdgcn_global_load_lds((const __attribute__((address_space(1))) void*)g,
                                   (__attribute__((address_space(3))) void*)l,
                                   16, 0, 0);
}
#define MFMA32(A, B, C) __builtin_amdgcn_mfma_f32_32x32x16_bf16(A, B, C, 0, 0, 0)

// ---------------- cast f32 -> bf16, 8 elems/thread ----------------
__global__ __launch_bounds__(256) void cast_f32_bf16(const float* __restrict__ in,
                                                     unsigned short* __restrict__ out,
                                                     int n8) {
  int i = blockIdx.x * 256 + threadIdx.x;
  if (i >= n8) return;
  float4 v0 = ((const float4*)in)[i * 2];
  float4 v1 = ((const float4*)in)[i * 2 + 1];
  ushort4 o0, o1;
  o0.x = f2bf(v0.x); o0.y = f2bf(v0.y); o0.z = f2bf(v0.z); o0.w = f2bf(v0.w);
  o1.x = f2bf(v1.x); o1.y = f2bf(v1.y); o1.z = f2bf(v1.z); o1.w = f2bf(v1.w);
  ((ushort4*)out)[i * 2] = o0;
  ((ushort4*)out)[i * 2 + 1] = o1;
}

// ---------------- weight transpose + cast: W[K][N] f32 -> Wt[N][K] bf16 ----------------
__global__ __launch_bounds__(256) void transpose_cast(const float* __restrict__ W,
                                                      unsigned short* __restrict__ Wt,
                                                      int N, int K) {
  __shared__ float tile[32][33];
  int n0 = blockIdx.x * 32, k0 = blockIdx.y * 32;
  int tx = threadIdx.x & 31;
  int ty = threadIdx.x >> 5; // 0..7
#pragma unroll
  for (int i = 0; i < 32; i += 8)
    tile[ty + i][tx] = W[(size_t)(k0 + ty + i) * N + n0 + tx];
  __syncthreads();
#pragma unroll
  for (int i = 0; i < 32; i += 8)
    Wt[(size_t)(n0 + ty + i) * K + k0 + tx] = f2bf(tile[tx][ty + i]);
}

// ---------------- V transpose: P1 v-region (b,s | kv,d) -> Vt[b][kv][d][s] ----------------
__global__ __launch_bounds__(256) void vtrans_kernel(const unsigned short* __restrict__ P1,
                                                     unsigned short* __restrict__ Vt) {
  // grid: (S/32, HD/32, B*NKV)
  __shared__ unsigned short tile[32][33];
  int s0 = blockIdx.x * 32, d0 = blockIdx.y * 32, bk = blockIdx.z;
  int b = bk >> 3, kv = bk & 7;
  int tx = threadIdx.x & 31, ty = threadIdx.x >> 5;
#pragma unroll
  for (int i = 0; i < 32; i += 8)
    tile[ty + i][tx] = P1[(size_t)(b * S_ + s0 + ty + i) * 3072 + 2560 + kv * 64 + d0 + tx];
  __syncthreads();
#pragma unroll
  for (int i = 0; i < 32; i += 8)
    Vt[(size_t)(bk * 64 + d0 + ty + i) * S_ + s0 + tx] = tile[tx][ty + i];
}

// ---------------- RoPE combine: Q = rope(P1q+P2q)*SCALE, K = rope(P1k+P2k) ----------------
__global__ __launch_bounds__(256) void combine_rope(const unsigned short* __restrict__ P1,
                                                    const unsigned short* __restrict__ P2,
                                                    const float* __restrict__ cosT,
                                                    const float* __restrict__ sinT,
                                                    unsigned short* __restrict__ Qb,
                                                    unsigned short* __restrict__ Kb) {
  int id = blockIdx.x * 256 + threadIdx.x;   // total B*S*640
  int row = id / 640;                        // b*S + s
  int grp = id - row * 640;
  int b = row >> 11;
  int s = row & 2047;
  bool isQ = grp < 512;
  int n = isQ ? grp * 4 : (grp - 512) * 4;
  int h = n >> 6;
  int d = n & 63;
  int base = isQ ? 0 : 2048;
  const int ld1 = 3072, ld2 = 2560;
  int pd = (d < 32) ? d + 32 : d - 32;
  float sign = (d < 32) ? -1.f : 1.f;
  int pcol = base + h * 64 + pd;

  ushort4 a1 = *(const ushort4*)&P1[(size_t)row * ld1 + base + n];
  ushort4 a2 = *(const ushort4*)&P2[(size_t)row * ld2 + base + n];
  ushort4 b1 = *(const ushort4*)&P1[(size_t)row * ld1 + pcol];
  ushort4 b2 = *(const ushort4*)&P2[(size_t)row * ld2 + pcol];
  float4 cv = *(const float4*)&cosT[(size_t)row * 64 + d];
  float4 sv = *(const float4*)&sinT[(size_t)row * 64 + d];
  float scale = isQ ? 0.125f : 1.0f;

  float xs[4] = { bf2f(a1.x) + bf2f(a2.x), bf2f(a1.y) + bf2f(a2.y),
                  bf2f(a1.z) + bf2f(a2.z), bf2f(a1.w) + bf2f(a2.w) };
  float xp[4] = { bf2f(b1.x) + bf2f(b2.x), bf2f(b1.y) + bf2f(b2.y),
                  bf2f(b1.z) + bf2f(b2.z), bf2f(b1.w) + bf2f(b2.w) };
  float cc[4] = { cv.x, cv.y, cv.z, cv.w };
  float ss[4] = { sv.x, sv.y, sv.z, sv.w };
  ushort4 o;
  unsigned short* op = (unsigned short*)&o;
#pragma unroll
  for (int i = 0; i < 4; ++i)
    op[i] = f2bf((xs[i] * cc[i] + sign * xp[i] * ss[i]) * scale);

  if (isQ)
    *(ushort4*)&Qb[((size_t)(b * NH_ + h) * S_ + s) * HD_ + d] = o;
  else
    *(ushort4*)&Kb[((size_t)(b * NKV_ + h) * S_ + s) * HD_ + d] = o;
}

// ---------------- m97-structure GEMM: C[M][N] = A[M][K](bf16) * Bt[N][K]^T ----------------
template <int OF32>
__global__ __launch_bounds__(256) void gemm_bt(const unsigned short* __restrict__ A,
                                               const unsigned short* __restrict__ Bt,
                                               void* __restrict__ Cv,
                                               int N, int K, int nbx) {
  __shared__ unsigned short lA[128 * 32];
  __shared__ unsigned short lB[128 * 32];
  int nwg = gridDim.x;
  int orig = blockIdx.x;
  int wgid = (orig & 7) * (nwg >> 3) + (orig >> 3);  // bijective: nwg % 8 == 0
  int bn = wgid % nbx;
  int bm = wgid / nbx;
  int t = threadIdx.x;
  int w = t >> 6, l = t & 63, g = l >> 4, c = l & 15;
  int wr = w >> 1, wc = w & 1;

  int srow = w * 16 + (l >> 2);
  int scol = (l & 3) * 8;
  const unsigned short* gA0 = A + (size_t)(bm * 128 + srow) * K + scol;
  const unsigned short* gA1 = A + (size_t)(bm * 128 + 64 + srow) * K + scol;
  const unsigned short* gB0 = Bt + (size_t)(bn * 128 + srow) * K + scol;
  const unsigned short* gB1 = Bt + (size_t)(bn * 128 + 64 + srow) * K + scol;
  unsigned short* lA0 = &lA[w * 512];
  unsigned short* lA1 = &lA[2048 + w * 512];
  unsigned short* lB0 = &lB[w * 512];
  unsigned short* lB1 = &lB[2048 + w * 512];

  f32x4 acc[4][4];
#pragma unroll
  for (int m = 0; m < 4; ++m)
#pragma unroll
    for (int n = 0; n < 4; ++n) acc[m][n] = 0.f;

  for (int k0 = 0; k0 < K; k0 += 32) {
    __syncthreads();
    gload_lds16(gA0 + k0, lA0);
    gload_lds16(gA1 + k0, lA1);
    gload_lds16(gB0 + k0, lB0);
    gload_lds16(gB1 + k0, lB1);
    __syncthreads();

    short8 a[4], bfr[4];
#pragma unroll
    for (int m = 0; m < 4; ++m)
      a[m] = *(const short8*)&lA[(wr * 64 + m * 16 + c) * 32 + g * 8];
#pragma unroll
    for (int n = 0; n < 4; ++n)
      bfr[n] = *(const short8*)&lB[(wc * 64 + n * 16 + c) * 32 + g * 8];
#pragma unroll
    for (int m = 0; m < 4; ++m)
#pragma unroll
      for (int n = 0; n < 4; ++n)
        acc[m][n] = __builtin_amdgcn_mfma_f32_16x16x32_bf16(a[m], bfr[n], acc[m][n], 0, 0, 0);
  }

#pragma unroll
  for (int m = 0; m < 4; ++m) {
#pragma unroll
    for (int n = 0; n < 4; ++n) {
#pragma unroll
      for (int r = 0; r < 4; ++r) {
        int row = bm * 128 + wr * 64 + m * 16 + g * 4 + r;
        int col = bn * 128 + wc * 64 + n * 16 + c;
        if constexpr (OF32)
          ((float*)Cv)[(size_t)row * N + col] = acc[m][n][r];
        else
          ((unsigned short*)Cv)[(size_t)row * N + col] = f2bf(acc[m][n][r]);
      }
    }
  }
}

// ---------------- causal GQA flash attention, 8-warp, paired-segment balanced ----------------
// Block = pair j: warps 0-3 cover q-segment j*128, warps 4-7 cover (15-j)*128.
// Both segments start at kv=0, so one staged K/V stream (nt = 32-2j tiles) serves both.
// Every block does exactly 136 warp-tiles -> uniform work across all 512 blocks.
__global__ __launch_bounds__(512) void attn_kernel(const unsigned short* __restrict__ Q,
                                                   const unsigned short* __restrict__ K,
                                                   const unsigned short* __restrict__ Vt,
                                                   unsigned short* __restrict__ attnOut) {
  __shared__ unsigned short lK[2][64 * 64]; // [64 kv][64 d], 16B slots XOR-swizzled by (row&7)
  __shared__ unsigned short lV[2][64 * 64]; // [64 d][64 kv], same swizzle

  int bx = blockIdx.x;
  int j = bx & 7;             // pair id
  int bh = bx >> 3;           // 0..63
  int head = bh & 31;
  int b = bh >> 5;
  int kvh = head >> 2;
  const unsigned short* Kp = K + (size_t)(b * NKV_ + kvh) * S_ * HD_;
  const unsigned short* Vp = Vt + (size_t)(b * NKV_ + kvh) * HD_ * S_;

  int t = threadIdx.x;
  int w = t >> 6, l = t & 63;
  int q32 = l & 31, hf = l >> 5;
  int qb_eff = (w < 4) ? j : (15 - j);
  int qbase_w = qb_eff * 128 + (w & 3) * 32;
  const unsigned short* Qp = Q + ((size_t)(b * NH_ + head) * S_ + qbase_w) * HD_;

  short8 qf[4];
  {
    const unsigned short* qrow = Qp + (size_t)q32 * HD_ + hf * 8;
#pragma unroll
    for (int kc = 0; kc < 4; ++kc)
      qf[kc] = *(const short8*)(qrow + kc * 16);
  }

  int srow = t >> 3;       // 0..63
  int sslot = t & 7;       // 0..7
  unsigned lOff = srow * 128 + ((sslot ^ (srow & 7)) << 4);
  const char* gK0 = (const char*)(Kp + (size_t)srow * 64 + sslot * 8);
  const char* gV0 = (const char*)(Vp + (size_t)srow * 2048 + sslot * 8);

  {
    int4 rk = *(const int4*)(gK0);
    int4 rv = *(const int4*)(gV0);
    *(int4*)((char*)lK[0] + lOff) = rk;
    *(int4*)((char*)lV[0] + lOff) = rv;
  }
  __syncthreads();

  f32x16 oA = 0.f, oB = 0.f;  // O[q=crow][d=q32 (+32 for oB)]
  float mrun = -1e30f, lrun = 0.f;

  int nt = 32 - 2 * j;        // high segment's tile count (covers low segment too)
  int cur = 0;
  for (int tI = 0; tI < nt; ++tI) {
    int kv0 = tI * 64;
    bool pf = (tI + 1 < nt);
    int4 nk, nv;
    if (pf) {
      nk = *(const int4*)(gK0 + (size_t)(kv0 + 64) * 128);
      nv = *(const int4*)(gV0 + (size_t)(kv0 + 64) * 2);
    }

    if (kv0 <= qbase_w + 31) {
      const char* lKc = (const char*)lK[cur];
      const char* lVc = (const char*)lV[cur];
      int swz = q32 & 7;

      f32x16 sA = 0.f, sB = 0.f;
      __builtin_amdgcn_s_setprio(1);
#pragma unroll
      for (int kc = 0; kc < 4; ++kc) {
        int cs = (kc << 1) | hf;
        short8 ak0 = *(const short8*)(lKc + q32 * 128 + ((cs ^ swz) << 4));
        short8 ak1 = *(const short8*)(lKc + (32 + q32) * 128 + ((cs ^ swz) << 4));
        sA = MFMA32(ak0, qf[kc], sA);
        sB = MFMA32(ak1, qf[kc], sB);
      }
      __builtin_amdgcn_s_setprio(0);

      if (kv0 + 63 > qbase_w) {
        int qg = qbase_w + q32;
#pragma unroll
        for (int r = 0; r < 16; ++r) {
          int kvr = kv0 + (r & 3) + ((r >> 2) << 3) + (hf << 2);
          if (kvr > qg) sA[r] = -1e30f;
          if (kvr + 32 > qg) sB[r] = -1e30f;
        }
      }

      float pmax = sA[0];
#pragma unroll
      for (int r = 1; r < 16; ++r) pmax = fmaxf(pmax, sA[r]);
#pragma unroll
      for (int r = 0; r < 16; ++r) pmax = fmaxf(pmax, sB[r]);
      pmax = fmaxf(pmax, __shfl_xor(pmax, 32, 64));

      if (!__all(pmax <= mrun + 8.f)) {
        float mnew = fmaxf(mrun, pmax);
        float sf = __expf(mrun - mnew);
        lrun *= sf;
        mrun = mnew;
#pragma unroll
        for (int r = 0; r < 16; ++r) {
          int src = (r & 3) + ((r >> 2) << 3) + (hf << 2);
          float sfr = __shfl(sf, src, 64);
          oA[r] *= sfr;
          oB[r] *= sfr;
        }
      }

      float rs = 0.f;
#pragma unroll
      for (int r = 0; r < 16; ++r) { sA[r] = __expf(sA[r] - mrun); rs += sA[r]; }
#pragma unroll
      for (int r = 0; r < 16; ++r) { sB[r] = __expf(sB[r] - mrun); rs += sB[r]; }
      rs += __shfl_xor(rs, 32, 64);
      lrun += rs;

      short8 paf[4];
      {
        unsigned c0 = cvtpk(sA[0], sA[1]), c1 = cvtpk(sA[2], sA[3]);
        unsigned c2 = cvtpk(sA[4], sA[5]), c3 = cvtpk(sA[6], sA[7]);
        pl32swap(c0, c2); pl32swap(c1, c3);
        paf[0] = mkfrag(c0, c1, c2, c3);
      }
      {
        unsigned c0 = cvtpk(sA[8], sA[9]),  c1 = cvtpk(sA[10], sA[11]);
        unsigned c2 = cvtpk(sA[12], sA[13]), c3 = cvtpk(sA[14], sA[15]);
        pl32swap(c0, c2); pl32swap(c1, c3);
        paf[1] = mkfrag(c0, c1, c2, c3);
      }
      {
        unsigned c0 = cvtpk(sB[0], sB[1]), c1 = cvtpk(sB[2], sB[3]);
        unsigned c2 = cvtpk(sB[4], sB[5]), c3 = cvtpk(sB[6], sB[7]);
        pl32swap(c0, c2); pl32swap(c1, c3);
        paf[2] = mkfrag(c0, c1, c2, c3);
      }
      {
        unsigned c0 = cvtpk(sB[8], sB[9]),  c1 = cvtpk(sB[10], sB[11]);
        unsigned c2 = cvtpk(sB[12], sB[13]), c3 = cvtpk(sB[14], sB[15]);
        pl32swap(c0, c2); pl32swap(c1, c3);
        paf[3] = mkfrag(c0, c1, c2, c3);
      }

      __builtin_amdgcn_s_setprio(1);
#pragma unroll
      for (int ks = 0; ks < 4; ++ks) {
        int cs = (ks << 1) | hf;
        short8 v0 = *(const short8*)(lVc + q32 * 128 + ((cs ^ swz) << 4));
        short8 v1 = *(const short8*)(lVc + (32 + q32) * 128 + ((cs ^ swz) << 4));
        oA = MFMA32(paf[ks], v0, oA);
        oB = MFMA32(paf[ks], v1, oB);
      }
      __builtin_amdgcn_s_setprio(0);
    }

    if (pf) {
      *(int4*)((char*)lK[cur ^ 1] + lOff) = nk;
      *(int4*)((char*)lV[cur ^ 1] + lOff) = nv;
    }
    __syncthreads();
    cur ^= 1;
  }

  float linv = 1.f / lrun;
#pragma unroll
  for (int r = 0; r < 16; ++r) {
    int src = (r & 3) + ((r >> 2) << 3) + (hf << 2);   // q = crow(r,hf)
    float li = __shfl(linv, src, 64);
    unsigned short* op = attnOut + ((size_t)(b * S_ + qbase_w + src)) * (NH_ * HD_) + head * 64;
    op[q32] = f2bf(oA[r] * li);
    op[32 + q32] = f2bf(oB[r] * li);
  }
}

extern "C" void kernel_launch(void* const* d_in, const int* in_sizes, int n_in,
                              void* d_out, int out_size, void* d_ws, size_t ws_size,
                              hipStream_t stream) {
  const float* hidden = (const float*)d_in[0];
  const float* bbox   = (const float*)d_in[1];
  const float* cosT   = (const float*)d_in[2];
  const float* sinT   = (const float*)d_in[3];
  const float* Wq  = (const float*)d_in[4];
  const float* Wk  = (const float*)d_in[5];
  const float* Wv  = (const float*)d_in[6];
  const float* Wo  = (const float*)d_in[7];
  const float* Wsq = (const float*)d_in[8];
  const float* Wsk = (const float*)d_in[9];

  char* ws = (char*)d_ws;
  size_t off = 0;
  auto alloc = [&](size_t bytes) {
    void* p = ws + off;
    off += (bytes + 255) & ~(size_t)255;
    return p;
  };
  unsigned short* WhT = (unsigned short*)alloc((size_t)3072 * 2048 * 2);
  unsigned short* WbT = (unsigned short*)alloc((size_t)2560 * 2048 * 2);
  unsigned short* WoT = (unsigned short*)alloc((size_t)2048 * 2048 * 2);
  unsigned short* P1  = (unsigned short*)alloc((size_t)4096 * 3072 * 2);
  unsigned short* P2  = (unsigned short*)alloc((size_t)4096 * 2560 * 2);
  unsigned short* Xh  = (unsigned short*)alloc((size_t)4096 * 2048 * 2);
  unsigned short* Xb  = (unsigned short*)alloc((size_t)4096 * 2048 * 2);
  // aliases into dead regions:
  unsigned short* attn = Xh;             // Xh dead after P1 gemm; attn written after
  unsigned short* Qb   = Xb;             // Xb dead after P2 gemm
  unsigned short* Kb   = Xb + (size_t)B_ * NH_ * S_ * HD_;
  unsigned short* Vt   = Kb + (size_t)B_ * NKV_ * S_ * HD_;

  dim3 blk(256);
  // input casts f32 -> bf16
  cast_f32_bf16<<<dim3(4096), blk, 0, stream>>>(hidden, Xh, 4096 * 2048 / 8);
  cast_f32_bf16<<<dim3(4096), blk, 0, stream>>>(bbox,   Xb, 4096 * 2048 / 8);

  // weight transpose+cast (concatenated N-major)
  transpose_cast<<<dim3(64, 64), blk, 0, stream>>>(Wq,  WhT, 2048, 2048);
  transpose_cast<<<dim3(16, 64), blk, 0, stream>>>(Wk,  WhT + (size_t)2048 * 2048, 512, 2048);
  transpose_cast<<<dim3(16, 64), blk, 0, stream>>>(Wv,  WhT + (size_t)2560 * 2048, 512, 2048);
  transpose_cast<<<dim3(64, 64), blk, 0, stream>>>(Wsq, WbT, 2048, 2048);
  transpose_cast<<<dim3(16, 64), blk, 0, stream>>>(Wsk, WbT + (size_t)2048 * 2048, 512, 2048);
  transpose_cast<<<dim3(64, 64), blk, 0, stream>>>(Wo,  WoT, 2048, 2048);

  // projections (m97 structure): grids are (M/128)*(N/128), all % 8 == 0
  gemm_bt<0><<<dim3(32 * 24), blk, 0, stream>>>(Xh, WhT, P1, 3072, 2048, 24);
  gemm_bt<0><<<dim3(32 * 20), blk, 0, stream>>>(Xb, WbT, P2, 2560, 2048, 20);

  // rope combine + V transpose (write into Xb region — Xb dead now)
  combine_rope<<<dim3((B_ * S_ * 640) / 256), blk, 0, stream>>>(P1, P2, cosT, sinT, Qb, Kb);
  vtrans_kernel<<<dim3(64, 2, 16), blk, 0, stream>>>(P1, Vt);

  // attention (writes attn = Xh region — Xh dead now)
  attn_kernel<<<dim3(512), dim3(512), 0, stream>>>(Qb, Kb, Vt, attn);

  // output projection (f32 out)
  gemm_bt<1><<<dim3(32 * 16), blk, 0, stream>>>(attn, WoT, d_out, 2048, 2048, 16);
}